// Round 1
// baseline (796.345 us; speedup 1.0000x reference)
//
#include <hip/hip_runtime.h>

#define L 2048
#define CIN 16
#define COUT 16
#define GROUPS 4
#define NEG_INF -1000000000.0f

// ---------------------------------------------------------------------------
// Kernel A: per-(channel,row) sparsemax threshold tau via Michelot iteration.
// tau solves sum(max(z - tau, 0)) = 1 over valid (causal) prefix of the row.
// One block (256 thr) per row; row cached in 8 regs/thread.
// ---------------------------------------------------------------------------
__global__ __launch_bounds__(256) void tau_kernel(const float* __restrict__ scores,
                                                  float* __restrict__ tau_out) {
    const int row = blockIdx.x;
    const int ch  = blockIdx.y;
    const int n   = row + 1;                      // valid causal prefix length
    const float* zrow = scores + ((size_t)ch * L + row) * L;
    const int tid = threadIdx.x;

    float v[8];
    float sum_l = 0.0f;
#pragma unroll
    for (int j = 0; j < 8; ++j) {
        int c = tid + j * 256;
        float x = NEG_INF;                        // sentinel: never enters support
        if (c < n) { x = zrow[c]; sum_l += x; }
        v[j] = x;
    }

    __shared__ float lds[8];
    __shared__ float bc[2];                       // broadcast: tau-related S, K

    // ---- initial full sum ----
    float s = sum_l;
#pragma unroll
    for (int off = 32; off; off >>= 1) s += __shfl_down(s, off, 64);
    const int wid  = tid >> 6;
    const int lane = tid & 63;
    if (lane == 0) lds[wid] = s;
    __syncthreads();
    if (tid == 0) bc[0] = lds[0] + lds[1] + lds[2] + lds[3];
    __syncthreads();
    float tau = (bc[0] - 1.0f) / (float)n;
    int k_prev = n;

    // ---- Michelot: shrink support until stable ----
    for (int it = 0; it < 48; ++it) {
        float sl = 0.0f, kl = 0.0f;
#pragma unroll
        for (int j = 0; j < 8; ++j) {
            if (v[j] > tau) { sl += v[j]; kl += 1.0f; }
        }
#pragma unroll
        for (int off = 32; off; off >>= 1) {
            sl += __shfl_down(sl, off, 64);
            kl += __shfl_down(kl, off, 64);
        }
        __syncthreads();                          // protect lds reuse
        if (lane == 0) { lds[wid] = sl; lds[4 + wid] = kl; }
        __syncthreads();
        if (tid == 0) {
            bc[0] = lds[0] + lds[1] + lds[2] + lds[3];
            bc[1] = lds[4] + lds[5] + lds[6] + lds[7];
        }
        __syncthreads();
        float S = bc[0];
        int   K = (int)bc[1];
        if (K == k_prev) break;                   // support stable -> converged
        tau = (S - 1.0f) / (float)K;
        k_prev = K;
    }

    if (tid == 0) tau_out[ch * L + row] = tau;
}

// ---------------------------------------------------------------------------
// Kernel B: grouped 3x3 conv over on-the-fly probs = max(score - tau, 0),
// causal-zeroed. Tile: 32 rows x 64 cols x 4 out-channels (one group).
// Thread t: out-channel (t>>6), column (t&63), slides 3-row window over 32 rows.
// ---------------------------------------------------------------------------
#define TR 32
#define TC 64
#define HR 34
#define HC 66
#define HCS 68   // LDS stride

__global__ __launch_bounds__(256) void conv_kernel(const float* __restrict__ scores,
                                                   const float* __restrict__ tau,
                                                   const float* __restrict__ weight,
                                                   const float* __restrict__ bias,
                                                   float* __restrict__ out) {
    const int c0 = blockIdx.x * TC;
    const int r0 = blockIdx.y * TR;
    const int g  = blockIdx.z;
    const int t  = threadIdx.x;

    // Tile entirely above the causal diagonal: pure zero-fill, no loads.
    if (c0 > r0 + TR - 1) {
        // 4 ch * 32 rows * 64 cols = 8192 floats = 2048 float4, 8 per thread
#pragma unroll
        for (int j = 0; j < 8; ++j) {
            int idx = t + j * 256;                // 0..2047
            int c4  = idx & 15;                   // 16 float4 per row
            int r   = (idx >> 4) & 31;
            int o   = idx >> 9;                   // 0..3
            float4* p = (float4*)(out + (((size_t)(g * 4 + o) * L + (r0 + r)) * L + c0)) + c4;
            *p = make_float4(0.f, 0.f, 0.f, 0.f);
        }
        return;
    }

    __shared__ float P[4][HR][HCS];               // probs tile + halo
    __shared__ float Wsh[4][4][9];                // [o][i][3x3]
    __shared__ float Tau[4][HR];

    // stage weights (group g) and tau halo
    if (t < 144) {
        int o = t / 36, rem = t % 36;
        Wsh[o][rem / 9][rem % 9] = weight[(g * 4 + o) * 36 + rem];
    }
    if (t < 136) {                                // 4 * 34
        int i = t / HR, hr = t % HR;
        int r = r0 - 1 + hr;
        Tau[i][hr] = (r >= 0 && r < L) ? tau[(g * 4 + i) * L + r] : 0.0f;
    }
    __syncthreads();

    // stage probs tile: 4 * 34 * 66 = 8976 elements
    for (int idx = t; idx < 4 * HR * HC; idx += 256) {
        int i   = idx / (HR * HC);
        int rem = idx % (HR * HC);
        int hr  = rem / HC;
        int hc  = rem % HC;
        int r = r0 - 1 + hr;
        int c = c0 - 1 + hc;
        float val = 0.0f;
        if (r >= 0 && r < L && c >= 0 && c <= r) {   // c<=r implies c<L
            float z = scores[((size_t)(g * 4 + i) * L + r) * L + c];
            val = fmaxf(z - Tau[i][hr], 0.0f);
        }
        P[i][hr][hc] = val;
    }
    __syncthreads();

    const int o   = t >> 6;
    const int col = t & 63;
    const int cg  = c0 + col;

    float w[4][9];
#pragma unroll
    for (int i = 0; i < 4; ++i)
#pragma unroll
        for (int k = 0; k < 9; ++k) w[i][k] = Wsh[o][i][k];
    const float b = bias[g * 4 + o];

    // sliding 3-row window per input channel
    float win[4][3][3];
#pragma unroll
    for (int i = 0; i < 4; ++i)
#pragma unroll
        for (int dx = 0; dx < 3; ++dx) {
            win[i][1][dx] = P[i][0][col + dx];
            win[i][2][dx] = P[i][1][col + dx];
        }

    const size_t outbase = (size_t)(g * 4 + o) * L * L;
    for (int rr = 0; rr < TR; ++rr) {
#pragma unroll
        for (int i = 0; i < 4; ++i)
#pragma unroll
            for (int dx = 0; dx < 3; ++dx) {
                win[i][0][dx] = win[i][1][dx];
                win[i][1][dx] = win[i][2][dx];
                win[i][2][dx] = P[i][rr + 2][col + dx];
            }
        float acc = b;
#pragma unroll
        for (int i = 0; i < 4; ++i)
#pragma unroll
            for (int dy = 0; dy < 3; ++dy)
#pragma unroll
                for (int dx = 0; dx < 3; ++dx)
                    acc = fmaf(win[i][dy][dx], w[i][dy * 3 + dx], acc);
        int r = r0 + rr;
        out[outbase + (size_t)r * L + cg] = (cg <= r) ? acc : 0.0f;
    }
}

extern "C" void kernel_launch(void* const* d_in, const int* in_sizes, int n_in,
                              void* d_out, int out_size, void* d_ws, size_t ws_size,
                              hipStream_t stream) {
    const float* scores = (const float*)d_in[0];
    const float* weight = (const float*)d_in[1];
    const float* bias   = (const float*)d_in[2];
    float* out = (float*)d_out;
    float* tau = (float*)d_ws;                    // 16*2048 floats = 128 KB

    dim3 gridA(L, CIN);
    tau_kernel<<<gridA, 256, 0, stream>>>(scores, tau);

    dim3 gridB(L / TC, L / TR, GROUPS);
    conv_kernel<<<gridB, 256, 0, stream>>>(scores, tau, weight, bias, out);
}

// Round 2
// 533.957 us; speedup vs baseline: 1.4914x; 1.4914x over previous
//
#include <hip/hip_runtime.h>

#define L 2048
#define CIN 16
#define GROUPS 4
#define NEG_INF -1000000000.0f

// ---------------------------------------------------------------------------
// Kernel A: sparsemax tau, ONE WAVE PER ROW (no barriers, no LDS).
// Michelot fixed-point: tau <- (sum_{z>tau} z - 1)/|{z>tau}|, init tau = max-1
// (support starts ~20 elems for Gaussian data -> ~4-6 iterations).
// Each lane holds 32 row elements (8 x float4, coalesced).
// ---------------------------------------------------------------------------
__global__ __launch_bounds__(256) void tau_kernel(const float* __restrict__ scores,
                                                  float* __restrict__ tau_out) {
    const int wid  = (blockIdx.x << 2) + (threadIdx.x >> 6); // global wave id
    const int lane = threadIdx.x & 63;
    const int ch   = wid >> 11;           // / 2048
    const int row  = wid & 2047;
    const int n    = row + 1;             // causal prefix length
    const float* zrow = scores + ((size_t)ch * L + row) * L;

    float v[32];
    float m = NEG_INF;
#pragma unroll
    for (int j = 0; j < 8; ++j) {
        int c4 = lane + (j << 6);         // float4 index, < 512 always
        int c  = c4 << 2;
        float4 z = make_float4(NEG_INF, NEG_INF, NEG_INF, NEG_INF);
        if (c < n) z = *((const float4*)zrow + c4);   // skip loads past row end
        v[4*j+0] = (c + 0 < n) ? z.x : NEG_INF;
        v[4*j+1] = (c + 1 < n) ? z.y : NEG_INF;
        v[4*j+2] = (c + 2 < n) ? z.z : NEG_INF;
        v[4*j+3] = (c + 3 < n) ? z.w : NEG_INF;
        m = fmaxf(m, fmaxf(fmaxf(v[4*j+0], v[4*j+1]), fmaxf(v[4*j+2], v[4*j+3])));
    }
    // wave max
#pragma unroll
    for (int d = 32; d; d >>= 1) m = fmaxf(m, __shfl_xor(m, d, 64));

    float tau = m - 1.0f;                 // lower bound on tau*, support superset
    int k_prev = -1;
    for (int it = 0; it < 64; ++it) {
        float S = 0.0f, Kf = 0.0f;
#pragma unroll
        for (int j = 0; j < 32; ++j) {
            if (v[j] > tau) { S += v[j]; Kf += 1.0f; }
        }
#pragma unroll
        for (int d = 32; d; d >>= 1) {
            S  += __shfl_xor(S,  d, 64);
            Kf += __shfl_xor(Kf, d, 64);
        }
        int K = (int)Kf;                  // exact: K <= 2048
        if (K == k_prev) break;           // nested supports + equal size => fixed point
        tau = (S - 1.0f) / Kf;
        k_prev = K;
    }
    if (lane == 0) tau_out[ch * L + row] = tau;
}

// ---------------------------------------------------------------------------
// Kernel B: grouped 3x3 conv over on-the-fly probs = max(score - tau, 0).
// Tile: 16 rows x 64 cols x 4 out-channels. LDS ~19.6 KB -> 8 blocks/CU.
// LDS layout: main cols at [0,64) (16B aligned, float4 staging),
// left halo col at [64], right halo col at [65], stride 68.
// Weights: wave-uniform (o = wave id) -> readfirstlane -> scalar loads.
// ---------------------------------------------------------------------------
#define TR 16
#define TC 64
#define HR 18
#define HCS 68

__global__ __launch_bounds__(256) void conv_kernel(const float* __restrict__ scores,
                                                   const float* __restrict__ tau,
                                                   const float* __restrict__ weight,
                                                   const float* __restrict__ bias,
                                                   float* __restrict__ out) {
    const int c0 = blockIdx.x * TC;
    const int r0 = blockIdx.y * TR;
    const int g  = blockIdx.z;
    const int t  = threadIdx.x;

    // Tile entirely above the causal diagonal: vectorized zero-fill, no loads.
    if (c0 > r0 + TR - 1) {
#pragma unroll
        for (int jj = 0; jj < 4; ++jj) {
            int idx = t + jj * 256;            // 0..1023
            int c4  = idx & 15;
            int r   = (idx >> 4) & 15;
            int o   = idx >> 8;                // 0..3
            float4* p = (float4*)(out + (((size_t)(g * 4 + o) * L + (r0 + r)) * L + c0)) + c4;
            *p = make_float4(0.f, 0.f, 0.f, 0.f);
        }
        return;
    }

    __shared__ __align__(16) float P[4][HR][HCS];

    // ---- stage probs: main region, float4, pow2 index math only ----
    for (int i = 0; i < 4; ++i) {
        const float* srcbase = scores + (size_t)(g * 4 + i) * L * L;
        const float* taubase = tau + (g * 4 + i) * L;
#pragma unroll
        for (int rnd = 0; rnd < 2; ++rnd) {
            int idx = t + rnd * 256;
            if (idx < HR * 16) {               // 288 float4 per channel
                int hr = idx >> 4;
                int c4 = idx & 15;
                int r  = r0 - 1 + hr;
                int cb = c0 + (c4 << 2);
                float4 val = make_float4(0.f, 0.f, 0.f, 0.f);
                if (r >= 0 && r < L && cb <= r) {
                    float tv = taubase[r];
                    float4 z = *((const float4*)(srcbase + (size_t)r * L) + (cb >> 2));
                    val.x = fmaxf(z.x - tv, 0.f);                      // cb <= r
                    val.y = (cb + 1 <= r) ? fmaxf(z.y - tv, 0.f) : 0.f;
                    val.z = (cb + 2 <= r) ? fmaxf(z.z - tv, 0.f) : 0.f;
                    val.w = (cb + 3 <= r) ? fmaxf(z.w - tv, 0.f) : 0.f;
                }
                *((float4*)&P[i][hr][c4 << 2]) = val;
            }
        }
    }
    // ---- halo columns: left (c0-1) -> slot 64, right (c0+64) -> slot 65 ----
    if (t < 144) {
        int side = t & 1;
        int j  = t >> 1;                       // 0..71
        int i  = j / 18;
        int hr = j - i * 18;
        int r  = r0 - 1 + hr;
        int c  = side ? (c0 + TC) : (c0 - 1);
        float val = 0.f;
        if (r >= 0 && r < L && c >= 0 && c <= r) {
            val = fmaxf(scores[((size_t)(g * 4 + i) * L + r) * L + c]
                        - tau[(g * 4 + i) * L + r], 0.f);
        }
        P[i][hr][64 + side] = val;
    }
    __syncthreads();

    // ---- compute: thread = (out-channel o, column col) ----
    const int o   = __builtin_amdgcn_readfirstlane(t >> 6);  // wave-uniform -> SGPR
    const int col = t & 63;
    const int cg  = c0 + col;

    float w[4][9];                             // scalar loads (uniform address)
#pragma unroll
    for (int i = 0; i < 4; ++i)
#pragma unroll
        for (int k = 0; k < 9; ++k) w[i][k] = weight[((g * 4 + o) * 4 + i) * 9 + k];
    const float b = bias[g * 4 + o];

    const int xl = (col == 0)  ? 64 : col - 1;
    const int xm = col;
    const int xr = (col == 63) ? 65 : col + 1;

    float win[4][3][3];
#pragma unroll
    for (int i = 0; i < 4; ++i) {
        win[i][1][0] = P[i][0][xl]; win[i][1][1] = P[i][0][xm]; win[i][1][2] = P[i][0][xr];
        win[i][2][0] = P[i][1][xl]; win[i][2][1] = P[i][1][xm]; win[i][2][2] = P[i][1][xr];
    }

    const size_t outbase = ((size_t)(g * 4 + o) * L + r0) * L + cg;
#pragma unroll
    for (int rr = 0; rr < TR; ++rr) {
#pragma unroll
        for (int i = 0; i < 4; ++i) {
#pragma unroll
            for (int dx = 0; dx < 3; ++dx) {
                win[i][0][dx] = win[i][1][dx];
                win[i][1][dx] = win[i][2][dx];
            }
            win[i][2][0] = P[i][rr + 2][xl];
            win[i][2][1] = P[i][rr + 2][xm];
            win[i][2][2] = P[i][rr + 2][xr];
        }
        float acc = b;
#pragma unroll
        for (int i = 0; i < 4; ++i)
#pragma unroll
            for (int dy = 0; dy < 3; ++dy)
#pragma unroll
                for (int dx = 0; dx < 3; ++dx)
                    acc = fmaf(win[i][dy][dx], w[i][3 * dy + dx], acc);
        out[outbase + (size_t)rr * L] = (cg <= r0 + rr) ? acc : 0.0f;
    }
}

extern "C" void kernel_launch(void* const* d_in, const int* in_sizes, int n_in,
                              void* d_out, int out_size, void* d_ws, size_t ws_size,
                              hipStream_t stream) {
    const float* scores = (const float*)d_in[0];
    const float* weight = (const float*)d_in[1];
    const float* bias   = (const float*)d_in[2];
    float* out = (float*)d_out;
    float* tau = (float*)d_ws;                 // 16*2048 floats = 128 KB

    tau_kernel<<<(CIN * L) / 4, 256, 0, stream>>>(scores, tau);

    dim3 gridB(L / TC, L / TR, GROUPS);
    conv_kernel<<<gridB, 256, 0, stream>>>(scores, tau, weight, bias, out);
}